// Round 2
// baseline (896.201 us; speedup 1.0000x reference)
//
#include <hip/hip_runtime.h>

#define NUM_RELS 19

// ---------------- CSR build ----------------
// cnt2[v*19+r] = #edges with dst=v, etype=r  (feeds both scan1 and layer1)

__global__ void hist2_kernel(const int* __restrict__ dst, const int* __restrict__ etype,
                             int* __restrict__ cnt2, int E) {
    int e = blockIdx.x * blockDim.x + threadIdx.x;
    if (e < E) atomicAdd(&cnt2[dst[e] * NUM_RELS + etype[e]], 1);
}

// chunk = 2048 nodes per block (256 threads x 8 nodes); per-node count = sum of 19 cnt2 entries
__global__ void scan1_kernel(const int* __restrict__ cnt2, int* __restrict__ row_start,
                             int* __restrict__ bsum, int N) {
    __shared__ int lds[256];
    int t = threadIdx.x;
    int base = blockIdx.x * 2048 + t * 8;
    int v[8];
    int s = 0;
#pragma unroll
    for (int k = 0; k < 8; ++k) {
        int c = 0;
        if (base + k < N) {
            const int* p = cnt2 + (size_t)(base + k) * NUM_RELS;
#pragma unroll
            for (int r = 0; r < NUM_RELS; ++r) c += p[r];
        }
        v[k] = c;
        s += c;
    }
    lds[t] = s;
    __syncthreads();
    for (int off = 1; off < 256; off <<= 1) {
        int x = (t >= off) ? lds[t - off] : 0;
        __syncthreads();
        lds[t] += x;
        __syncthreads();
    }
    int run = lds[t] - s;  // exclusive prefix of this thread's chunk
#pragma unroll
    for (int k = 0; k < 8; ++k) {
        if (base + k < N) row_start[base + k] = run;
        run += v[k];
    }
    if (t == 255) bsum[blockIdx.x] = lds[255];
}

__global__ void scan2_kernel(int* __restrict__ bsum, int NB) {
    __shared__ int lds[256];
    int t = threadIdx.x;
    int v = (t < NB) ? bsum[t] : 0;
    lds[t] = v;
    __syncthreads();
    for (int off = 1; off < 256; off <<= 1) {
        int x = (t >= off) ? lds[t - off] : 0;
        __syncthreads();
        lds[t] += x;
        __syncthreads();
    }
    if (t < NB) bsum[t] = lds[t] - v;  // exclusive
}

__global__ void scan3_kernel(int* __restrict__ row_start, int* __restrict__ cursor,
                             const int* __restrict__ bsum, int N, int E) {
    int i = blockIdx.x * blockDim.x + threadIdx.x;
    if (i < N) {
        int v = row_start[i] + bsum[i >> 11];
        row_start[i] = v;
        cursor[i] = v;
    } else if (i == N) {
        row_start[N] = E;
    }
}

// scatter edge meta into CSR order: layer23 then reads src/etype coalesced, no eid indirection
__global__ void scatter_kernel(const int* __restrict__ src, const int* __restrict__ dst,
                               const int* __restrict__ etype, int* __restrict__ cursor,
                               int* __restrict__ ssrc, int* __restrict__ setype, int E) {
    int e = blockIdx.x * blockDim.x + threadIdx.x;
    if (e < E) {
        int p = atomicAdd(&cursor[dst[e]], 1);
        ssrc[p] = src[e];
        setype[p] = etype[e];
    }
}

// ---------------- Layer 1 (closed form): h1[v][o] = relu(b1[o] + sum_r cnt2[v][r]*W1[r][o]) ----------------

__global__ __launch_bounds__(256) void layer1_kernel(
    const int* __restrict__ cnt2, const float* __restrict__ W1,
    const float* __restrict__ b1, float* __restrict__ h1, int N) {
    __shared__ float W1s[NUM_RELS * 32];
    __shared__ float b1s[32];
    for (int t = threadIdx.x; t < NUM_RELS * 32; t += blockDim.x) W1s[t] = W1[t];
    if (threadIdx.x < 32) b1s[threadIdx.x] = b1[threadIdx.x];
    __syncthreads();

    int hw = (blockIdx.x * blockDim.x + threadIdx.x) >> 5;  // node id
    int o = threadIdx.x & 31;
    if (hw >= N) return;
    const int* c = cnt2 + (size_t)hw * NUM_RELS;
    float acc = b1s[o];
#pragma unroll
    for (int r = 0; r < NUM_RELS; ++r) acc += (float)c[r] * W1s[r * 32 + o];
    h1[(size_t)hw * 32 + o] = fmaxf(acc, 0.f);
}

// ---------------- Layer 2 + 3 fused, software-pipelined ----------------
// Per 32-lane half-wave: one node, lane = output channel o.
// Ping-pong two h-rows (A/B, 8 float4 each) so edge j+1's gather overlaps edge j's FMAs.

#define W2T_PAD 36
#define W2T_FLOATS (NUM_RELS * 32 * W2T_PAD)

__global__ __launch_bounds__(1024) void layer23_kernel(
    const float* __restrict__ h1, const int* __restrict__ row_start,
    const int* __restrict__ ssrc, const int* __restrict__ setype,
    const float* __restrict__ W2, const float* __restrict__ b2,
    const float* __restrict__ W3, const float* __restrict__ b3,
    float* __restrict__ out, int N) {
    extern __shared__ float lds[];
    float* W2T = lds;                    // [19][32][36] (o-major, i padded)
    float* W3s = lds + W2T_FLOATS;       // [32][32]

    for (int t = threadIdx.x; t < NUM_RELS * 1024; t += blockDim.x) {
        int r = t >> 10, rem = t & 1023, i = rem >> 5, o = rem & 31;
        W2T[(r * 32 + o) * W2T_PAD + i] = W2[t];
    }
    for (int t = threadIdx.x; t < 1024; t += blockDim.x) W3s[t] = W3[t];
    __syncthreads();

    int hw = (blockIdx.x * blockDim.x + threadIdx.x) >> 5;  // node id
    int o = threadIdx.x & 31;
    if (hw >= N) return;
    int start = row_start[hw], end = row_start[hw + 1];

    float acc = 0.f;
    for (int base = start; base < end; base += 32) {
        int idx = base + o;
        int s_l = (idx < end) ? ssrc[idx] : 0;    // coalesced
        int r_l = (idx < end) ? setype[idx] : 0;  // coalesced
        int cnt = min(32, end - base);

        float4 A[8], B[8];
        int s0 = __shfl(s_l, 0, 32);
        int rA = __shfl(r_l, 0, 32);
        {
            const float4* hp = (const float4*)(h1 + (size_t)s0 * 32);
#pragma unroll
            for (int c = 0; c < 8; ++c) A[c] = hp[c];
        }
        int j = 0;
        while (j + 1 < cnt) {
            int sB = __shfl(s_l, j + 1, 32);
            int rB = __shfl(r_l, j + 1, 32);
            {
                const float4* hp = (const float4*)(h1 + (size_t)sB * 32);
#pragma unroll
                for (int c = 0; c < 8; ++c) B[c] = hp[c];
            }
            {  // compute edge j from A
                const float* wp = W2T + (rA * 32 + o) * W2T_PAD;
#pragma unroll
                for (int c = 0; c < 8; ++c) {
                    float4 w4 = *(const float4*)(wp + c * 4);
                    acc = fmaf(A[c].x, w4.x, acc);
                    acc = fmaf(A[c].y, w4.y, acc);
                    acc = fmaf(A[c].z, w4.z, acc);
                    acc = fmaf(A[c].w, w4.w, acc);
                }
            }
            if (j + 2 < cnt) {  // prefetch edge j+2 into A
                int sA = __shfl(s_l, j + 2, 32);
                rA = __shfl(r_l, j + 2, 32);
                const float4* hp = (const float4*)(h1 + (size_t)sA * 32);
#pragma unroll
                for (int c = 0; c < 8; ++c) A[c] = hp[c];
            }
            {  // compute edge j+1 from B
                const float* wp = W2T + (rB * 32 + o) * W2T_PAD;
#pragma unroll
                for (int c = 0; c < 8; ++c) {
                    float4 w4 = *(const float4*)(wp + c * 4);
                    acc = fmaf(B[c].x, w4.x, acc);
                    acc = fmaf(B[c].y, w4.y, acc);
                    acc = fmaf(B[c].z, w4.z, acc);
                    acc = fmaf(B[c].w, w4.w, acc);
                }
            }
            j += 2;
        }
        if (j < cnt) {  // odd tail: edge j sits in A
            const float* wp = W2T + (rA * 32 + o) * W2T_PAD;
#pragma unroll
            for (int c = 0; c < 8; ++c) {
                float4 w4 = *(const float4*)(wp + c * 4);
                acc = fmaf(A[c].x, w4.x, acc);
                acc = fmaf(A[c].y, w4.y, acc);
                acc = fmaf(A[c].z, w4.z, acc);
                acc = fmaf(A[c].w, w4.w, acc);
            }
        }
    }
    acc += b2[o];
    float h2v = fmaxf(acc, 0.f);

    // layer 3 via cross-lane broadcast of h2
    float acc3 = b3[o];
#pragma unroll
    for (int i = 0; i < 32; ++i) {
        float hi = __shfl(h2v, i, 32);
        acc3 = fmaf(hi, W3s[i * 32 + o], acc3);
    }
    out[(size_t)hw * 32 + o] = acc3;
}

// ---------------- Host launcher ----------------

extern "C" void kernel_launch(void* const* d_in, const int* in_sizes, int n_in,
                              void* d_out, int out_size, void* d_ws, size_t ws_size,
                              hipStream_t stream) {
    const int* src   = (const int*)d_in[0];
    const int* dst   = (const int*)d_in[1];
    const int* etype = (const int*)d_in[2];
    const float* W1  = (const float*)d_in[4];
    const float* b1  = (const float*)d_in[5];
    const float* W2  = (const float*)d_in[6];
    const float* b2  = (const float*)d_in[7];
    const float* W3  = (const float*)d_in[8];
    const float* b3  = (const float*)d_in[9];
    float* out = (float*)d_out;

    int E = in_sizes[0];
    int N = out_size / 32;

    char* ws = (char*)d_ws;
    size_t off = 0;
    auto alloc = [&](size_t bytes) {
        void* p = ws + off;
        off = (off + bytes + 255) & ~(size_t)255;
        return p;
    };
    float* h1      = (float*)alloc((size_t)N * 32 * 4);
    int* cnt2      = (int*)alloc((size_t)N * NUM_RELS * 4);
    int* row_start = (int*)alloc((size_t)(N + 1) * 4);
    int* cursor    = (int*)alloc((size_t)N * 4);
    int* bsum      = (int*)alloc(256 * 4);
    int* ssrc      = (int*)alloc((size_t)E * 4);
    int* setype    = (int*)alloc((size_t)E * 4);

    hipMemsetAsync(cnt2, 0, (size_t)N * NUM_RELS * 4, stream);
    hist2_kernel<<<(E + 255) / 256, 256, 0, stream>>>(dst, etype, cnt2, E);
    int NB = (N + 2047) / 2048;
    scan1_kernel<<<NB, 256, 0, stream>>>(cnt2, row_start, bsum, N);
    scan2_kernel<<<1, 256, 0, stream>>>(bsum, NB);
    scan3_kernel<<<(N + 1 + 255) / 256, 256, 0, stream>>>(row_start, cursor, bsum, N, E);
    scatter_kernel<<<(E + 255) / 256, 256, 0, stream>>>(src, dst, etype, cursor, ssrc, setype, E);
    layer1_kernel<<<(N + 7) / 8, 256, 0, stream>>>(cnt2, W1, b1, h1, N);

    const int LDS23 = (W2T_FLOATS + 32 * 32) * 4;
    hipFuncSetAttribute(reinterpret_cast<const void*>(layer23_kernel),
                        hipFuncAttributeMaxDynamicSharedMemorySize, LDS23);
    layer23_kernel<<<(N + 31) / 32, 1024, LDS23, stream>>>(h1, row_start, ssrc, setype,
                                                           W2, b2, W3, b3, out, N);
}

// Round 3
// 737.045 us; speedup vs baseline: 1.2159x; 1.2159x over previous
//
#include <hip/hip_runtime.h>

#define NUM_RELS 19

// ---------------- CSR build ----------------
// cnt2[v*19+r] = #edges with dst=v, etype=r  (feeds both scan1 and layer1)

__global__ void hist2_kernel(const int* __restrict__ dst, const int* __restrict__ etype,
                             int* __restrict__ cnt2, int E) {
    int e = blockIdx.x * blockDim.x + threadIdx.x;
    if (e < E) atomicAdd(&cnt2[dst[e] * NUM_RELS + etype[e]], 1);
}

// chunk = 2048 nodes per block (256 threads x 8 nodes); per-node count = sum of 19 cnt2 entries
__global__ void scan1_kernel(const int* __restrict__ cnt2, int* __restrict__ row_start,
                             int* __restrict__ bsum, int N) {
    __shared__ int lds[256];
    int t = threadIdx.x;
    int base = blockIdx.x * 2048 + t * 8;
    int v[8];
    int s = 0;
#pragma unroll
    for (int k = 0; k < 8; ++k) {
        int c = 0;
        if (base + k < N) {
            const int* p = cnt2 + (size_t)(base + k) * NUM_RELS;
#pragma unroll
            for (int r = 0; r < NUM_RELS; ++r) c += p[r];
        }
        v[k] = c;
        s += c;
    }
    lds[t] = s;
    __syncthreads();
    for (int off = 1; off < 256; off <<= 1) {
        int x = (t >= off) ? lds[t - off] : 0;
        __syncthreads();
        lds[t] += x;
        __syncthreads();
    }
    int run = lds[t] - s;  // exclusive prefix of this thread's chunk
#pragma unroll
    for (int k = 0; k < 8; ++k) {
        if (base + k < N) row_start[base + k] = run;
        run += v[k];
    }
    if (t == 255) bsum[blockIdx.x] = lds[255];
}

__global__ void scan2_kernel(int* __restrict__ bsum, int NB) {
    __shared__ int lds[256];
    int t = threadIdx.x;
    int v = (t < NB) ? bsum[t] : 0;
    lds[t] = v;
    __syncthreads();
    for (int off = 1; off < 256; off <<= 1) {
        int x = (t >= off) ? lds[t - off] : 0;
        __syncthreads();
        lds[t] += x;
        __syncthreads();
    }
    if (t < NB) bsum[t] = lds[t] - v;  // exclusive
}

__global__ void scan3_kernel(int* __restrict__ row_start, int* __restrict__ cursor,
                             const int* __restrict__ bsum, int N, int E) {
    int i = blockIdx.x * blockDim.x + threadIdx.x;
    if (i < N) {
        int v = row_start[i] + bsum[i >> 11];
        row_start[i] = v;
        cursor[i] = v;
    } else if (i == N) {
        row_start[N] = E;
    }
}

// scatter packed edge meta (src<<5 | etype) into CSR order — ONE int per edge
__global__ void scatter_kernel(const int* __restrict__ src, const int* __restrict__ dst,
                               const int* __restrict__ etype, int* __restrict__ cursor,
                               int* __restrict__ smeta, int E) {
    int e = blockIdx.x * blockDim.x + threadIdx.x;
    if (e < E) {
        int p = atomicAdd(&cursor[dst[e]], 1);
        smeta[p] = (src[e] << 5) | etype[e];
    }
}

// ---------------- Layer 1 (closed form): h1[v][o] = relu(b1[o] + sum_r cnt2[v][r]*W1[r][o]) ----------------

__global__ __launch_bounds__(256) void layer1_kernel(
    const int* __restrict__ cnt2, const float* __restrict__ W1,
    const float* __restrict__ b1, float* __restrict__ h1, int N) {
    __shared__ float W1s[NUM_RELS * 32];
    __shared__ float b1s[32];
    for (int t = threadIdx.x; t < NUM_RELS * 32; t += blockDim.x) W1s[t] = W1[t];
    if (threadIdx.x < 32) b1s[threadIdx.x] = b1[threadIdx.x];
    __syncthreads();

    int hw = (blockIdx.x * blockDim.x + threadIdx.x) >> 5;  // node id
    int o = threadIdx.x & 31;
    if (hw >= N) return;
    const int* c = cnt2 + (size_t)hw * NUM_RELS;
    float acc = b1s[o];
#pragma unroll
    for (int r = 0; r < NUM_RELS; ++r) acc += (float)c[r] * W1s[r * 32 + o];
    h1[(size_t)hw * 32 + o] = fmaxf(acc, 0.f);
}

// ---------------- Layer 2 + 3 fused, software-pipelined ----------------
// Per 32-lane half-wave: one node, lane = output channel o.
// Ping-pong two h-rows (A/B, 8 float4 each) so edge j+1's gather overlaps edge j's FMAs.
// __launch_bounds__(1024, 4): 16 waves/CU (what the 90KB LDS allows anyway) -> VGPR cap 128,
// so the A/B pipeline buffers (64 VGPRs) stay in registers. Round-2's (1024) default capped
// at 64 VGPR and spilled them to scratch (WRITE_SIZE 402MB).

#define W2T_PAD 36
#define W2T_FLOATS (NUM_RELS * 32 * W2T_PAD)

__global__ __launch_bounds__(1024, 4) void layer23_kernel(
    const float* __restrict__ h1, const int* __restrict__ row_start,
    const int* __restrict__ smeta,
    const float* __restrict__ W2, const float* __restrict__ b2,
    const float* __restrict__ W3, const float* __restrict__ b3,
    float* __restrict__ out, int N) {
    extern __shared__ float lds[];
    float* W2T = lds;                    // [19][32][36] (o-major, i padded)
    float* W3s = lds + W2T_FLOATS;       // [32][32]

    for (int t = threadIdx.x; t < NUM_RELS * 1024; t += blockDim.x) {
        int r = t >> 10, rem = t & 1023, i = rem >> 5, o = rem & 31;
        W2T[(r * 32 + o) * W2T_PAD + i] = W2[t];
    }
    for (int t = threadIdx.x; t < 1024; t += blockDim.x) W3s[t] = W3[t];
    __syncthreads();

    int o = threadIdx.x & 31;

    for (int v0 = blockIdx.x * 32; v0 < N; v0 += gridDim.x * 32) {
        int hw = v0 + (threadIdx.x >> 5);  // node id
        if (hw >= N) continue;
        int start = row_start[hw], end = row_start[hw + 1];

        float acc = 0.f;
        for (int base = start; base < end; base += 32) {
            int idx = base + o;
            int m_l = (idx < end) ? smeta[idx] : 0;  // coalesced packed (src<<5|etype)
            int cnt = min(32, end - base);

            float4 A[8], B[8];
            int m0 = __shfl(m_l, 0, 32);
            int rA = m0 & 31;
            {
                const float4* hp = (const float4*)(h1 + (size_t)(m0 >> 5) * 32);
#pragma unroll
                for (int c = 0; c < 8; ++c) A[c] = hp[c];
            }
            int j = 0;
            while (j + 1 < cnt) {
                int mB = __shfl(m_l, j + 1, 32);
                int rB = mB & 31;
                {
                    const float4* hp = (const float4*)(h1 + (size_t)(mB >> 5) * 32);
#pragma unroll
                    for (int c = 0; c < 8; ++c) B[c] = hp[c];
                }
                {  // compute edge j from A
                    const float* wp = W2T + (rA * 32 + o) * W2T_PAD;
#pragma unroll
                    for (int c = 0; c < 8; ++c) {
                        float4 w4 = *(const float4*)(wp + c * 4);
                        acc = fmaf(A[c].x, w4.x, acc);
                        acc = fmaf(A[c].y, w4.y, acc);
                        acc = fmaf(A[c].z, w4.z, acc);
                        acc = fmaf(A[c].w, w4.w, acc);
                    }
                }
                if (j + 2 < cnt) {  // prefetch edge j+2 into A
                    int mA = __shfl(m_l, j + 2, 32);
                    rA = mA & 31;
                    const float4* hp = (const float4*)(h1 + (size_t)(mA >> 5) * 32);
#pragma unroll
                    for (int c = 0; c < 8; ++c) A[c] = hp[c];
                }
                {  // compute edge j+1 from B
                    const float* wp = W2T + (rB * 32 + o) * W2T_PAD;
#pragma unroll
                    for (int c = 0; c < 8; ++c) {
                        float4 w4 = *(const float4*)(wp + c * 4);
                        acc = fmaf(B[c].x, w4.x, acc);
                        acc = fmaf(B[c].y, w4.y, acc);
                        acc = fmaf(B[c].z, w4.z, acc);
                        acc = fmaf(B[c].w, w4.w, acc);
                    }
                }
                j += 2;
            }
            if (j < cnt) {  // odd tail: edge j sits in A
                const float* wp = W2T + (rA * 32 + o) * W2T_PAD;
#pragma unroll
                for (int c = 0; c < 8; ++c) {
                    float4 w4 = *(const float4*)(wp + c * 4);
                    acc = fmaf(A[c].x, w4.x, acc);
                    acc = fmaf(A[c].y, w4.y, acc);
                    acc = fmaf(A[c].z, w4.z, acc);
                    acc = fmaf(A[c].w, w4.w, acc);
                }
            }
        }
        acc += b2[o];
        float h2v = fmaxf(acc, 0.f);

        // layer 3 via cross-lane broadcast of h2
        float acc3 = b3[o];
#pragma unroll
        for (int i = 0; i < 32; ++i) {
            float hi = __shfl(h2v, i, 32);
            acc3 = fmaf(hi, W3s[i * 32 + o], acc3);
        }
        out[(size_t)hw * 32 + o] = acc3;
    }
}

// ---------------- Host launcher ----------------

extern "C" void kernel_launch(void* const* d_in, const int* in_sizes, int n_in,
                              void* d_out, int out_size, void* d_ws, size_t ws_size,
                              hipStream_t stream) {
    const int* src   = (const int*)d_in[0];
    const int* dst   = (const int*)d_in[1];
    const int* etype = (const int*)d_in[2];
    const float* W1  = (const float*)d_in[4];
    const float* b1  = (const float*)d_in[5];
    const float* W2  = (const float*)d_in[6];
    const float* b2  = (const float*)d_in[7];
    const float* W3  = (const float*)d_in[8];
    const float* b3  = (const float*)d_in[9];
    float* out = (float*)d_out;

    int E = in_sizes[0];
    int N = out_size / 32;

    char* ws = (char*)d_ws;
    size_t off = 0;
    auto alloc = [&](size_t bytes) {
        void* p = ws + off;
        off = (off + bytes + 255) & ~(size_t)255;
        return p;
    };
    float* h1      = (float*)alloc((size_t)N * 32 * 4);
    int* cnt2      = (int*)alloc((size_t)N * NUM_RELS * 4);
    int* row_start = (int*)alloc((size_t)(N + 1) * 4);
    int* cursor    = (int*)alloc((size_t)N * 4);
    int* bsum      = (int*)alloc(256 * 4);
    int* smeta     = (int*)alloc((size_t)E * 4);

    hipMemsetAsync(cnt2, 0, (size_t)N * NUM_RELS * 4, stream);
    hist2_kernel<<<(E + 255) / 256, 256, 0, stream>>>(dst, etype, cnt2, E);
    int NB = (N + 2047) / 2048;
    scan1_kernel<<<NB, 256, 0, stream>>>(cnt2, row_start, bsum, N);
    scan2_kernel<<<1, 256, 0, stream>>>(bsum, NB);
    scan3_kernel<<<(N + 1 + 255) / 256, 256, 0, stream>>>(row_start, cursor, bsum, N, E);
    scatter_kernel<<<(E + 255) / 256, 256, 0, stream>>>(src, dst, etype, cursor, smeta, E);
    layer1_kernel<<<(N + 7) / 8, 256, 0, stream>>>(cnt2, W1, b1, h1, N);

    const int LDS23 = (W2T_FLOATS + 32 * 32) * 4;
    hipFuncSetAttribute(reinterpret_cast<const void*>(layer23_kernel),
                        hipFuncAttributeMaxDynamicSharedMemorySize, LDS23);
    layer23_kernel<<<1024, 1024, LDS23, stream>>>(h1, row_start, smeta,
                                                  W2, b2, W3, b3, out, N);
}